// Round 7
// baseline (202.363 us; speedup 1.0000x reference)
//
#include <hip/hip_runtime.h>
#include <hip/hip_bf16.h>

#define HW 262144            // 512*512
#define IW 512
#define TW 64
#define TH 8
#define PW 514               // padded plane width
#define PP 264196            // 514*514 px per padded plane image

typedef __attribute__((ext_vector_type(8))) short short8;
typedef __attribute__((ext_vector_type(4))) float f32x4;
typedef __attribute__((ext_vector_type(4))) unsigned int uint4v;

static __device__ inline unsigned int bpack2(float a, float b) {
  __hip_bfloat16 ha = __float2bfloat16(a);
  __hip_bfloat16 hb = __float2bfloat16(b);
  unsigned short ua = *reinterpret_cast<unsigned short*>(&ha);
  unsigned short ub = *reinterpret_cast<unsigned short*>(&hb);
  return (unsigned int)ua | ((unsigned int)ub << 16);
}

// ---------------- k_zero: zero 1-px borders of the 4 padded planes ----------
__global__ __launch_bounds__(256) void k_zero(uint4v* __restrict__ xP0,
                                              uint4v* __restrict__ xP1,
                                              uint4v* __restrict__ fP0,
                                              uint4v* __restrict__ fP1) {
  int pl = blockIdx.x >> 3, b = blockIdx.x & 7;
  uint4v* base = (pl == 0 ? xP0 : pl == 1 ? xP1 : pl == 2 ? fP0 : fP1) +
                 (size_t)b * PP;
  uint4v z = {0, 0, 0, 0};
  for (int i = threadIdx.x; i < 2052; i += 256) {
    int pp;
    if (i < 514) pp = i;                              // top row
    else if (i < 1028) pp = 513 * PW + (i - 514);     // bottom row
    else if (i < 1540) pp = (i - 1028 + 1) * PW;      // left col
    else pp = (i - 1540 + 1) * PW + 513;              // right col
    base[pp] = z;
  }
}

// ---------------- k_xc: x (NCHW f32) -> xP0/xP1 (padded bf16 ch-blocks) -----
__global__ __launch_bounds__(256) void k_xc(const float* __restrict__ x,
                                            uint4v* __restrict__ xP0,
                                            uint4v* __restrict__ xP1) {
  for (int it = 0; it < 4; ++it) {
    int idx = blockIdx.x * 1024 + it * 256 + threadIdx.x;   // 2M px
    int b = idx >> 18, gofs = idx & (HW - 1);
    const float* xb = x + (size_t)b * 16 * HW + gofs;
    int gh = gofs >> 9, gw = gofs & 511;
    size_t pp = (size_t)b * PP + (gh + 1) * PW + gw + 1;
    float a0 = xb[0],       a1 = xb[HW],      a2 = xb[2 * HW],  a3 = xb[3 * HW];
    float a4 = xb[4 * HW],  a5 = xb[5 * HW],  a6 = xb[6 * HW],  a7 = xb[7 * HW];
    xP0[pp] = uint4v{bpack2(a0, a1), bpack2(a2, a3), bpack2(a4, a5),
                     bpack2(a6, a7)};
    float b0 = xb[8 * HW],  b1 = xb[9 * HW],  b2 = xb[10 * HW], b3 = xb[11 * HW];
    float b4 = xb[12 * HW], b5 = xb[13 * HW], b6 = xb[14 * HW], b7 = xb[15 * HW];
    xP1[pp] = uint4v{bpack2(b0, b1), bpack2(b2, b3), bpack2(b4, b5),
                     bpack2(b6, b7)};
  }
}

// ------- k_fuse: fuse planes (padded bf16) + GAP partials (k_gap fused) -----
__global__ __launch_bounds__(256) void k_fuse(
    const float* __restrict__ y, const float* __restrict__ fuse_w,
    const float* __restrict__ fuse_b, uint4v* __restrict__ fP0,
    uint4v* __restrict__ fP1, float* __restrict__ partial) {
  __shared__ float fw[80], fb[16];
  __shared__ float red[4][16];
  int tid = threadIdx.x;
  if (tid < 80) fw[tid] = fuse_w[tid];
  if (tid < 16) fb[tid] = fuse_b[tid];
  __syncthreads();

  int b = blockIdx.x >> 7, chunk = blockIdx.x & 127;
  const float* yb = y + (size_t)b * 5 * HW;
  uint4v* f0 = fP0 + (size_t)b * PP;
  uint4v* f1 = fP1 + (size_t)b * PP;
  int gof0 = chunk * 2048;

  float sums[16];
#pragma unroll
  for (int o = 0; o < 16; ++o) sums[o] = 0.f;

#pragma unroll 1
  for (int i = 0; i < 2048; i += 256) {
    int gofs = gof0 + i + tid;
    float yv[5];
#pragma unroll
    for (int c = 0; c < 5; ++c) yv[c] = yb[c * HW + gofs];
    float fo[16];
#pragma unroll
    for (int o = 0; o < 16; ++o) {
      float a = fb[o];
#pragma unroll
      for (int c = 0; c < 5; ++c) a = fmaf(fw[o * 5 + c], yv[c], a);
      fo[o] = fmaxf(a, 0.f);
      sums[o] += fo[o];
    }
    int gh = gofs >> 9, gw = gofs & 511;
    int pp = (gh + 1) * PW + gw + 1;
    f0[pp] = uint4v{bpack2(fo[0], fo[1]), bpack2(fo[2], fo[3]),
                    bpack2(fo[4], fo[5]), bpack2(fo[6], fo[7])};
    f1[pp] = uint4v{bpack2(fo[8], fo[9]), bpack2(fo[10], fo[11]),
                    bpack2(fo[12], fo[13]), bpack2(fo[14], fo[15])};
  }

  int lane = tid & 63, wv = tid >> 6;
#pragma unroll
  for (int o = 0; o < 16; ++o) {
    float v = sums[o];
    for (int off = 32; off > 0; off >>= 1) v += __shfl_down(v, off);
    if (lane == 0) red[wv][o] = v;
  }
  __syncthreads();
  if (tid < 16)
    partial[blockIdx.x * 16 + tid] =
        red[0][tid] + red[1][tid] + red[2][tid] + red[3][tid];
}

// ---------------- k_se: SE MLP + fold se into boundary weights --------------
__global__ __launch_bounds__(256) void k_se(
    const float* __restrict__ partial, const float* __restrict__ se_w1,
    const float* __restrict__ se_w2, const float* __restrict__ bd_w,
    float* __restrict__ bd_eff) {
  int tid = threadIdx.x;
  int b = tid >> 5, sub = tid & 31;
  float g[16];
#pragma unroll
  for (int c = 0; c < 16; ++c) g[c] = 0.f;
#pragma unroll
  for (int k = 0; k < 4; ++k) {
    const float* p = partial + (b * 128 + sub + k * 32) * 16;
#pragma unroll
    for (int c = 0; c < 16; ++c) g[c] += p[c];
  }
#pragma unroll
  for (int c = 0; c < 16; ++c) {
    float v = g[c];
    v += __shfl_xor(v, 1);  v += __shfl_xor(v, 2);
    v += __shfl_xor(v, 4);  v += __shfl_xor(v, 8);
    v += __shfl_xor(v, 16);
    g[c] = v * (1.f / 262144.f);
  }
  if (sub == 0) {
    float h[16];
#pragma unroll
    for (int j = 0; j < 16; ++j) {
      float s = 0.f;
#pragma unroll
      for (int c = 0; c < 16; ++c) s += g[c] * se_w1[j * 16 + c];
      h[j] = fmaxf(s, 0.f);
    }
#pragma unroll
    for (int i = 0; i < 5; ++i) {
      float s = 0.f;
#pragma unroll
      for (int j = 0; j < 16; ++j) s += h[j] * se_w2[i * 16 + j];
      float se = 1.f / (1.f + expf(-s));
      bd_eff[b * 10 + i]     = bd_w[i] * se;
      bd_eff[b * 10 + 5 + i] = bd_w[5 + i] * se;
    }
  }
}

// ---------------- k_bsc: boundary softmax fg prob per px --------------------
__global__ __launch_bounds__(256) void k_bsc(const float* __restrict__ y,
                                             const float* __restrict__ bd_eff,
                                             const float* __restrict__ bd_b,
                                             float* __restrict__ bscaleP) {
  __shared__ float bde[10], bdb[2];
  int tid = threadIdx.x;
  int b = blockIdx.x >> 7, chunk = blockIdx.x & 127;
  if (tid < 10) bde[tid] = bd_eff[b * 10 + tid];
  if (tid < 2) bdb[tid] = bd_b[tid];
  __syncthreads();
  const float* yb = y + (size_t)b * 5 * HW;
  int gof0 = chunk * 2048;
#pragma unroll 1
  for (int i = 0; i < 2048; i += 256) {
    int gofs = gof0 + i + tid;
    float bl0 = bdb[0], bl1 = bdb[1];
#pragma unroll
    for (int c = 0; c < 5; ++c) {
      float yv = yb[c * HW + gofs];
      bl0 = fmaf(bde[c], yv, bl0);
      bl1 = fmaf(bde[5 + c], yv, bl1);
    }
    bscaleP[(size_t)b * HW + gofs] = 1.f / (1.f + __expf(bl0 - bl1));
  }
}

// ---------------- k_prep: repack fc_w -> wTab[s][oc][ci] bf16 ---------------
__global__ void k_prep(const float* __restrict__ fc_w,
                       unsigned short* __restrict__ wTab) {
  int i = blockIdx.x * 256 + threadIdx.x;
  if (i < 4608) {
    int ci = i & 31, rest = i >> 5;
    int oc = rest & 15, s = rest >> 4;
    float v = fc_w[(oc * 32 + ci) * 9 + s];
    __hip_bfloat16 h = __float2bfloat16(v);
    wTab[i] = *reinterpret_cast<unsigned short*>(&h);
  }
}

// ---------------- k_main2: LDS-free direct-global MFMA conv -----------------
// 256 thr = 4 waves; tile 64x8; wave wv owns rows 2wv,2wv+1 (8 groups of 16px).
// B-fragment = one global dwordx4 from the padded bf16 plane of this lane's q.
__global__ __launch_bounds__(256) void k_main2(
    const unsigned short* __restrict__ xP0, const unsigned short* __restrict__ xP1,
    const unsigned short* __restrict__ fP0, const unsigned short* __restrict__ fP1,
    const unsigned short* __restrict__ wTab, const float* __restrict__ bscaleP,
    const float* __restrict__ fc_b, const float* __restrict__ fm_w,
    const float* __restrict__ fm_b, const float* __restrict__ cv_w,
    const float* __restrict__ cv_b, float* __restrict__ out) {
  __shared__ float s_fm[32], s_fmb[2], s_cv[16], s_cvb[16], s_fcb[16];
  int tid = threadIdx.x;
  if (tid < 32) s_fm[tid] = fm_w[tid];
  else if (tid < 34) s_fmb[tid - 32] = fm_b[tid - 32];
  else if (tid < 50) s_cv[tid - 34]  = cv_w[tid - 34];
  else if (tid < 66) s_cvb[tid - 50] = cv_b[tid - 50];
  else if (tid < 82) s_fcb[tid - 66] = fc_b[tid - 66];

  int bsel = blockIdx.z;
  int h0 = blockIdx.y * TH;
  int w0 = blockIdx.x * TW;
  int lane = tid & 63, wv = tid >> 6;
  int l15 = lane & 15, q = lane >> 4;

  short8 afrag[9];
#pragma unroll
  for (int s = 0; s < 9; ++s)
    afrag[s] = *reinterpret_cast<const short8*>(wTab + (s * 16 + l15) * 32 + q * 8);

  const unsigned short* plane = q == 0 ? xP0 : q == 1 ? xP1 : q == 2 ? fP0 : fP1;
  const short8* pl = reinterpret_cast<const short8*>(plane) + (size_t)bsel * PP;

  __syncthreads();

  int pb[8];
  f32x4 acc[8];
#pragma unroll
  for (int g = 0; g < 8; ++g) {
    int row = 2 * wv + (g >> 2), c0 = (g & 3) * 16;
    pb[g] = (h0 + row) * PW + w0 + c0 + l15;
    acc[g] = f32x4{0.f, 0.f, 0.f, 0.f};
  }
#pragma unroll
  for (int kh = 0; kh < 3; ++kh) {
#pragma unroll
    for (int kw = 0; kw < 3; ++kw) {
      short8 a = afrag[kh * 3 + kw];
      short8 bf[8];
#pragma unroll
      for (int g = 0; g < 8; ++g) bf[g] = pl[pb[g] + kh * PW + kw];
#pragma unroll
      for (int g = 0; g < 8; ++g)
        acc[g] = __builtin_amdgcn_mfma_f32_16x16x32_bf16(a, bf[g], acc[g], 0, 0, 0);
    }
  }

  // ---- epilogue ----
  float pm0[8], pm1[8];
#pragma unroll
  for (int g = 0; g < 8; ++g) {
    float p0 = 0.f, p1 = 0.f;
#pragma unroll
    for (int j = 0; j < 4; ++j) {
      int oc = q * 4 + j;
      float fv = fmaxf(acc[g][j] + s_fcb[oc], 0.f);
      p0 = fmaf(s_fm[oc], fv, p0);
      p1 = fmaf(s_fm[16 + oc], fv, p1);
    }
    pm0[g] = p0; pm1[g] = p1;
  }
#pragma unroll
  for (int g = 0; g < 8; ++g) pm0[g] += __shfl_xor(pm0[g], 16);
#pragma unroll
  for (int g = 0; g < 8; ++g) pm1[g] += __shfl_xor(pm1[g], 16);
#pragma unroll
  for (int g = 0; g < 8; ++g) pm0[g] += __shfl_xor(pm0[g], 32);
#pragma unroll
  for (int g = 0; g < 8; ++g) pm1[g] += __shfl_xor(pm1[g], 32);

  const float* bsb = bscaleP + (size_t)bsel * HW;
  float* outb = out + (size_t)bsel * 16 * HW;
#pragma unroll
  for (int g = 0; g < 8; ++g) {
    int row = 2 * wv + (g >> 2), c0 = (g & 3) * 16;
    int gofs = (h0 + row) * IW + w0 + c0 + l15;
    float mscale =
        1.f / (1.f + __expf((pm0[g] + s_fmb[0]) - (pm1[g] + s_fmb[1])));
    float sc = fminf(fmaxf(mscale + bsb[gofs], 0.f), 1.f);
#pragma unroll
    for (int j = 0; j < 4; ++j) {
      int oc = q * 4 + j;
      outb[(size_t)oc * HW + gofs] = fmaf(s_cv[oc], sc, s_cvb[oc]);
    }
  }
}

// ============ fallback path (ws too small): round-6 fused kernel ============
#define HLW 66
#define NHALO 660
#define ROWU 40

__global__ __launch_bounds__(256) void k_gap(
    const float* __restrict__ y, const float* __restrict__ fuse_w,
    const float* __restrict__ fuse_b, float* __restrict__ partial) {
  __shared__ float fw[80], fb[16];
  __shared__ float red[4][16];
  int tid = threadIdx.x;
  if (tid < 80) fw[tid] = fuse_w[tid];
  if (tid < 16) fb[tid] = fuse_b[tid];
  __syncthreads();
  int b = blockIdx.x >> 7, chunk = blockIdx.x & 127;
  const float* yb = y + (size_t)b * 5 * HW + chunk * 2048;
  float sums[16];
#pragma unroll
  for (int o = 0; o < 16; ++o) sums[o] = 0.f;
  for (int i = 0; i < 2048; i += 256) {
    int p = i + tid;
    float yv[5];
#pragma unroll
    for (int c = 0; c < 5; ++c) yv[c] = yb[c * HW + p];
#pragma unroll
    for (int o = 0; o < 16; ++o) {
      float a = fb[o];
#pragma unroll
      for (int c = 0; c < 5; ++c) a = fmaf(fw[o * 5 + c], yv[c], a);
      sums[o] += fmaxf(a, 0.f);
    }
  }
  int lane = tid & 63, wv = tid >> 6;
#pragma unroll
  for (int o = 0; o < 16; ++o) {
    float v = sums[o];
    for (int off = 32; off > 0; off >>= 1) v += __shfl_down(v, off);
    if (lane == 0) red[wv][o] = v;
  }
  __syncthreads();
  if (tid < 16)
    partial[blockIdx.x * 16 + tid] =
        red[0][tid] + red[1][tid] + red[2][tid] + red[3][tid];
}

__global__ __launch_bounds__(256) void k_main_fb(
    const float* __restrict__ x, const float* __restrict__ y,
    const float* __restrict__ fuse_w, const float* __restrict__ fuse_b,
    const unsigned short* __restrict__ wTab,
    const float* __restrict__ bd_eff, const float* __restrict__ bd_b,
    const float* __restrict__ fc_b,
    const float* __restrict__ fm_w, const float* __restrict__ fm_b,
    const float* __restrict__ cv_w, const float* __restrict__ cv_b,
    float* __restrict__ out) {
  __shared__ unsigned short tile[NHALO * ROWU];
  __shared__ float s_fw[80], s_fb[16], s_bde[10], s_bdb[2], s_fm[32],
      s_fmb[2], s_cv[16], s_cvb[16], s_fcb[16];
  int tid = threadIdx.x;
  int bsel = blockIdx.z, h0 = blockIdx.y * TH, w0 = blockIdx.x * TW;
  if (tid < 80) s_fw[tid] = fuse_w[tid];
  else if (tid < 96)  s_fb[tid - 80]   = fuse_b[tid - 80];
  else if (tid < 106) s_bde[tid - 96]  = bd_eff[bsel * 10 + tid - 96];
  else if (tid < 108) s_bdb[tid - 106] = bd_b[tid - 106];
  else if (tid < 140) s_fm[tid - 108]  = fm_w[tid - 108];
  else if (tid < 142) s_fmb[tid - 140] = fm_b[tid - 140];
  else if (tid < 158) s_cv[tid - 142]  = cv_w[tid - 142];
  else if (tid < 174) s_cvb[tid - 158] = cv_b[tid - 158];
  else if (tid < 190) s_fcb[tid - 174] = fc_b[tid - 174];
  int lane = tid & 63, wv = tid >> 6, l15 = lane & 15, q = lane >> 4;
  short8 afrag[9];
#pragma unroll
  for (int s = 0; s < 9; ++s)
    afrag[s] = *reinterpret_cast<const short8*>(wTab + (s * 16 + l15) * 32 + q * 8);
  __syncthreads();
  const float* yb = y + (size_t)bsel * 5 * HW;
  const float* xb = x + (size_t)bsel * 16 * HW;
#pragma unroll 1
  for (int p = tid; p < NHALO; p += 256) {
    int hr = p / HLW, wc = p - hr * HLW;
    int gh = h0 - 1 + hr, gw = w0 - 1 + wc;
    bool valid = (gh >= 0) & (gh < IW) & (gw >= 0) & (gw < IW);
    uint4v* dst = reinterpret_cast<uint4v*>(&tile[p * ROWU]);
    if (valid) {
      int gofs = gh * IW + gw;
      {
        float a0 = xb[gofs],          a1 = xb[HW + gofs];
        float a2 = xb[2 * HW + gofs], a3 = xb[3 * HW + gofs];
        float a4 = xb[4 * HW + gofs], a5 = xb[5 * HW + gofs];
        float a6 = xb[6 * HW + gofs], a7 = xb[7 * HW + gofs];
        dst[0] = uint4v{bpack2(a0, a1), bpack2(a2, a3),
                        bpack2(a4, a5), bpack2(a6, a7)};
      }
      {
        float a0 = xb[8 * HW + gofs],  a1 = xb[9 * HW + gofs];
        float a2 = xb[10 * HW + gofs], a3 = xb[11 * HW + gofs];
        float a4 = xb[12 * HW + gofs], a5 = xb[13 * HW + gofs];
        float a6 = xb[14 * HW + gofs], a7 = xb[15 * HW + gofs];
        dst[1] = uint4v{bpack2(a0, a1), bpack2(a2, a3),
                        bpack2(a4, a5), bpack2(a6, a7)};
      }
      float yv[5];
#pragma unroll
      for (int c = 0; c < 5; ++c) yv[c] = yb[c * HW + gofs];
      float fo[8];
#pragma unroll
      for (int o = 0; o < 8; ++o) {
        float a = s_fb[o];
#pragma unroll
        for (int c = 0; c < 5; ++c) a = fmaf(s_fw[o * 5 + c], yv[c], a);
        fo[o] = fmaxf(a, 0.f);
      }
      dst[2] = uint4v{bpack2(fo[0], fo[1]), bpack2(fo[2], fo[3]),
                      bpack2(fo[4], fo[5]), bpack2(fo[6], fo[7])};
#pragma unroll
      for (int o = 0; o < 8; ++o) {
        float a = s_fb[8 + o];
#pragma unroll
        for (int c = 0; c < 5; ++c) a = fmaf(s_fw[(8 + o) * 5 + c], yv[c], a);
        fo[o] = fmaxf(a, 0.f);
      }
      dst[3] = uint4v{bpack2(fo[0], fo[1]), bpack2(fo[2], fo[3]),
                      bpack2(fo[4], fo[5]), bpack2(fo[6], fo[7])};
      float bl0 = s_bdb[0], bl1 = s_bdb[1];
#pragma unroll
      for (int c = 0; c < 5; ++c) {
        bl0 = fmaf(s_bde[c], yv[c], bl0);
        bl1 = fmaf(s_bde[5 + c], yv[c], bl1);
      }
      *reinterpret_cast<float*>(&tile[p * ROWU + 32]) =
          1.f / (1.f + __expf(bl0 - bl1));
    } else {
      uint4v z = {0, 0, 0, 0};
      dst[0] = z; dst[1] = z; dst[2] = z; dst[3] = z;
      *reinterpret_cast<float*>(&tile[p * ROWU + 32]) = 0.f;
    }
  }
  __syncthreads();
  const char* tb = reinterpret_cast<const char*>(tile);
  unsigned bofs[8];
  f32x4 acc[8];
#pragma unroll
  for (int g = 0; g < 8; ++g) {
    int row = 2 * wv + (g >> 2), c0 = (g & 3) * 16;
    bofs[g] = (unsigned)((row * HLW + c0 + l15) * (ROWU * 2) + q * 16);
    acc[g] = f32x4{0.f, 0.f, 0.f, 0.f};
  }
#pragma unroll
  for (int kh = 0; kh < 3; ++kh) {
#pragma unroll
    for (int kw = 0; kw < 3; ++kw) {
      short8 a = afrag[kh * 3 + kw];
#pragma unroll
      for (int g = 0; g < 8; ++g) {
        short8 bfr = *reinterpret_cast<const short8*>(
            tb + bofs[g] + (kh * HLW + kw) * (ROWU * 2));
        acc[g] = __builtin_amdgcn_mfma_f32_16x16x32_bf16(a, bfr, acc[g], 0, 0, 0);
      }
    }
  }
  float pm0[8], pm1[8];
#pragma unroll
  for (int g = 0; g < 8; ++g) {
    float p0 = 0.f, p1 = 0.f;
#pragma unroll
    for (int j = 0; j < 4; ++j) {
      int oc = q * 4 + j;
      float fv = fmaxf(acc[g][j] + s_fcb[oc], 0.f);
      p0 = fmaf(s_fm[oc], fv, p0);
      p1 = fmaf(s_fm[16 + oc], fv, p1);
    }
    pm0[g] = p0; pm1[g] = p1;
  }
#pragma unroll
  for (int g = 0; g < 8; ++g) pm0[g] += __shfl_xor(pm0[g], 16);
#pragma unroll
  for (int g = 0; g < 8; ++g) pm1[g] += __shfl_xor(pm1[g], 16);
#pragma unroll
  for (int g = 0; g < 8; ++g) pm0[g] += __shfl_xor(pm0[g], 32);
#pragma unroll
  for (int g = 0; g < 8; ++g) pm1[g] += __shfl_xor(pm1[g], 32);
  float* outb = out + (size_t)bsel * 16 * HW;
#pragma unroll
  for (int g = 0; g < 8; ++g) {
    int row = 2 * wv + (g >> 2), c0 = (g & 3) * 16;
    int gofs = (h0 + row) * IW + w0 + c0 + l15;
    float mscale =
        1.f / (1.f + __expf((pm0[g] + s_fmb[0]) - (pm1[g] + s_fmb[1])));
    float bsc = *reinterpret_cast<const float*>(
        tb + ((row + 1) * HLW + c0 + l15 + 1) * (ROWU * 2) + 64);
    float sc = fminf(fmaxf(mscale + bsc, 0.f), 1.f);
#pragma unroll
    for (int j = 0; j < 4; ++j) {
      int oc = q * 4 + j;
      outb[(size_t)oc * HW + gofs] = fmaf(s_cv[oc], sc, s_cvb[oc]);
    }
  }
}

extern "C" void kernel_launch(void* const* d_in, const int* in_sizes, int n_in,
                              void* d_out, int out_size, void* d_ws, size_t ws_size,
                              hipStream_t stream) {
  const float* x      = (const float*)d_in[0];
  const float* y      = (const float*)d_in[1];
  const float* fuse_w = (const float*)d_in[2];
  const float* fuse_b = (const float*)d_in[3];
  const float* se_w1  = (const float*)d_in[4];
  const float* se_w2  = (const float*)d_in[5];
  const float* bd_w   = (const float*)d_in[6];
  const float* bd_b   = (const float*)d_in[7];
  const float* fc_w   = (const float*)d_in[8];
  const float* fc_b   = (const float*)d_in[9];
  const float* fm_w   = (const float*)d_in[10];
  const float* fm_b   = (const float*)d_in[11];
  const float* cv_w   = (const float*)d_in[12];
  const float* cv_b   = (const float*)d_in[13];
  float* out = (float*)d_out;

  char* ws = (char*)d_ws;
  float* partial = (float*)ws;                                 // 64 KB
  float* bd_eff  = partial + 1024 * 16;                        // 320 B
  unsigned short* wTab = (unsigned short*)(ws + 65856);        // 9216 B
  size_t off = 75264;                                          // 256-aligned
  const size_t PLB = (size_t)8 * PP * 16;                      // 33.8 MB/plane
  unsigned short* xP0 = (unsigned short*)(ws + off);
  unsigned short* xP1 = (unsigned short*)(ws + off + PLB);
  unsigned short* fP0 = (unsigned short*)(ws + off + 2 * PLB);
  unsigned short* fP1 = (unsigned short*)(ws + off + 3 * PLB);
  float* bscaleP = (float*)(ws + off + 4 * PLB);               // 8 MB
  size_t need = off + 4 * PLB + (size_t)8 * HW * 4;

  if (ws_size >= need) {
    k_zero<<<32, 256, 0, stream>>>((uint4v*)xP0, (uint4v*)xP1, (uint4v*)fP0,
                                   (uint4v*)fP1);
    k_xc<<<2048, 256, 0, stream>>>(x, (uint4v*)xP0, (uint4v*)xP1);
    k_fuse<<<1024, 256, 0, stream>>>(y, fuse_w, fuse_b, (uint4v*)fP0,
                                     (uint4v*)fP1, partial);
    k_se<<<1, 256, 0, stream>>>(partial, se_w1, se_w2, bd_w, bd_eff);
    k_bsc<<<1024, 256, 0, stream>>>(y, bd_eff, bd_b, bscaleP);
    k_prep<<<18, 256, 0, stream>>>(fc_w, wTab);
    k_main2<<<dim3(8, 64, 8), 256, 0, stream>>>(
        xP0, xP1, fP0, fP1, wTab, bscaleP, fc_b, fm_w, fm_b, cv_w, cv_b, out);
  } else {
    k_gap<<<1024, 256, 0, stream>>>(y, fuse_w, fuse_b, partial);
    k_se<<<1, 256, 0, stream>>>(partial, se_w1, se_w2, bd_w, bd_eff);
    k_prep<<<18, 256, 0, stream>>>(fc_w, wTab);
    k_main_fb<<<dim3(8, 64, 8), 256, 0, stream>>>(
        x, y, fuse_w, fuse_b, wTab, bd_eff, bd_b, fc_b, fm_w, fm_b, cv_w, cv_b,
        out);
  }
}

// Round 8
// 154.038 us; speedup vs baseline: 1.3137x; 1.3137x over previous
//
#include <hip/hip_runtime.h>
#include <hip/hip_bf16.h>

#define HW 262144            // 512*512
#define IW 512
#define TW 64
#define TH 8
#define HLW 66               // TW+2
#define NHALO 660            // 66*10
#define ROWU 40              // ushorts/halo px: 32B x | 32B fuse | 4B bscale | pad

typedef __attribute__((ext_vector_type(8))) short short8;
typedef __attribute__((ext_vector_type(4))) float f32x4;
typedef __attribute__((ext_vector_type(4))) unsigned int uint4v;

static __device__ inline unsigned int bpack2(float a, float b) {
  __hip_bfloat16 ha = __float2bfloat16(a);
  __hip_bfloat16 hb = __float2bfloat16(b);
  unsigned short ua = *reinterpret_cast<unsigned short*>(&ha);
  unsigned short ub = *reinterpret_cast<unsigned short*>(&hb);
  return (unsigned int)ua | ((unsigned int)ub << 16);
}

// ---- k_fuse: fuse MLP once per px -> packed bf16 (32B/px) + GAP partials ----
__global__ __launch_bounds__(256) void k_fuse(
    const float* __restrict__ y, const float* __restrict__ fuse_w,
    const float* __restrict__ fuse_b, unsigned short* __restrict__ fuseP,
    float* __restrict__ partial) {
  __shared__ float fw[80], fb[16];
  __shared__ float red[4][16];
  int tid = threadIdx.x;
  if (tid < 80) fw[tid] = fuse_w[tid];
  if (tid < 16) fb[tid] = fuse_b[tid];
  __syncthreads();

  int b = blockIdx.x >> 7, chunk = blockIdx.x & 127;
  const float* yb = y + (size_t)b * 5 * HW;
  int gof0 = chunk * 2048;

  float sums[16];
#pragma unroll
  for (int o = 0; o < 16; ++o) sums[o] = 0.f;

#pragma unroll 1
  for (int i = 0; i < 2048; i += 256) {
    int gofs = gof0 + i + tid;
    float yv[5];
#pragma unroll
    for (int c = 0; c < 5; ++c) yv[c] = yb[c * HW + gofs];
    float fo[16];
#pragma unroll
    for (int o = 0; o < 16; ++o) {
      float a = fb[o];
#pragma unroll
      for (int c = 0; c < 5; ++c) a = fmaf(fw[o * 5 + c], yv[c], a);
      fo[o] = fmaxf(a, 0.f);
      sums[o] += fo[o];
    }
    size_t po = ((size_t)b * HW + gofs) * 16;
    uint4v* fp = reinterpret_cast<uint4v*>(fuseP + po);
    fp[0] = uint4v{bpack2(fo[0], fo[1]), bpack2(fo[2], fo[3]),
                   bpack2(fo[4], fo[5]), bpack2(fo[6], fo[7])};
    fp[1] = uint4v{bpack2(fo[8], fo[9]), bpack2(fo[10], fo[11]),
                   bpack2(fo[12], fo[13]), bpack2(fo[14], fo[15])};
  }

  int lane = tid & 63, wv = tid >> 6;
#pragma unroll
  for (int o = 0; o < 16; ++o) {
    float v = sums[o];
    for (int off = 32; off > 0; off >>= 1) v += __shfl_down(v, off);
    if (lane == 0) red[wv][o] = v;
  }
  __syncthreads();
  if (tid < 16)
    partial[blockIdx.x * 16 + tid] =
        red[0][tid] + red[1][tid] + red[2][tid] + red[3][tid];
}

// ---- k_se2: SE MLP -> bd_eff, plus fc_w -> wTab repack (one launch) --------
__global__ __launch_bounds__(256) void k_se2(
    const float* __restrict__ partial, const float* __restrict__ se_w1,
    const float* __restrict__ se_w2, const float* __restrict__ bd_w,
    const float* __restrict__ fc_w, float* __restrict__ bd_eff,
    unsigned short* __restrict__ wTab) {
  int tid = threadIdx.x;
  // part 1: SE (8 batches x 32 threads)
  {
    int b = tid >> 5, sub = tid & 31;
    float g[16];
#pragma unroll
    for (int c = 0; c < 16; ++c) g[c] = 0.f;
#pragma unroll
    for (int k = 0; k < 4; ++k) {
      const float* p = partial + (b * 128 + sub + k * 32) * 16;
#pragma unroll
      for (int c = 0; c < 16; ++c) g[c] += p[c];
    }
#pragma unroll
    for (int c = 0; c < 16; ++c) {
      float v = g[c];
      v += __shfl_xor(v, 1);  v += __shfl_xor(v, 2);
      v += __shfl_xor(v, 4);  v += __shfl_xor(v, 8);
      v += __shfl_xor(v, 16);
      g[c] = v * (1.f / 262144.f);
    }
    if (sub == 0) {
      float h[16];
#pragma unroll
      for (int j = 0; j < 16; ++j) {
        float s = 0.f;
#pragma unroll
        for (int c = 0; c < 16; ++c) s += g[c] * se_w1[j * 16 + c];
        h[j] = fmaxf(s, 0.f);
      }
#pragma unroll
      for (int i = 0; i < 5; ++i) {
        float s = 0.f;
#pragma unroll
        for (int j = 0; j < 16; ++j) s += h[j] * se_w2[i * 16 + j];
        float se = 1.f / (1.f + expf(-s));
        bd_eff[b * 10 + i]     = bd_w[i] * se;
        bd_eff[b * 10 + 5 + i] = bd_w[5 + i] * se;
      }
    }
  }
  // part 2: wTab repack (independent of part 1)
  for (int i = tid; i < 4608; i += 256) {
    int ci = i & 31, rest = i >> 5;
    int oc = rest & 15, s = rest >> 4;
    float v = fc_w[(oc * 32 + ci) * 9 + s];
    __hip_bfloat16 h = __float2bfloat16(v);
    wTab[i] = *reinterpret_cast<unsigned short*>(&h);
  }
}

// ---- k_main3: LDS-staged MFMA conv; cheap staging (fuse precomputed) -------
// 256 thr = 4 waves; tile 64x8; wave wv owns rows 2wv,2wv+1 (8 groups).
__global__ __launch_bounds__(256) void k_main3(
    const float* __restrict__ x, const float* __restrict__ y,
    const unsigned short* __restrict__ fuseP,
    const unsigned short* __restrict__ wTab,
    const float* __restrict__ bd_eff, const float* __restrict__ bd_b,
    const float* __restrict__ fc_b,
    const float* __restrict__ fm_w, const float* __restrict__ fm_b,
    const float* __restrict__ cv_w, const float* __restrict__ cv_b,
    float* __restrict__ out) {
  __shared__ unsigned short tile[NHALO * ROWU];   // 52800 B
  __shared__ float s_bde[10], s_bdb[2], s_fm[32], s_fmb[2], s_cv[16],
      s_cvb[16], s_fcb[16];

  int tid = threadIdx.x;
  int bsel = blockIdx.z;
  int h0 = blockIdx.y * TH;
  int w0 = blockIdx.x * TW;

  if (tid < 10) s_bde[tid] = bd_eff[bsel * 10 + tid];
  else if (tid < 12)  s_bdb[tid - 10] = bd_b[tid - 10];
  else if (tid < 44)  s_fm[tid - 12]  = fm_w[tid - 12];
  else if (tid < 46)  s_fmb[tid - 44] = fm_b[tid - 44];
  else if (tid < 62)  s_cv[tid - 46]  = cv_w[tid - 46];
  else if (tid < 78)  s_cvb[tid - 62] = cv_b[tid - 62];
  else if (tid < 94)  s_fcb[tid - 78] = fc_b[tid - 78];

  int lane = tid & 63, wv = tid >> 6;
  int l15 = lane & 15, q = lane >> 4;

  short8 afrag[9];
#pragma unroll
  for (int s = 0; s < 9; ++s)
    afrag[s] = *reinterpret_cast<const short8*>(wTab + (s * 16 + l15) * 32 + q * 8);

  __syncthreads();

  // ---- staging: x (16 coalesced dwords) + fuse copy (2 dwordx4) + bscale ----
  const float* yb = y + (size_t)bsel * 5 * HW;
  const float* xb = x + (size_t)bsel * 16 * HW;
#pragma unroll 1
  for (int p = tid; p < NHALO; p += 256) {
    int hr = p / HLW, wc = p - hr * HLW;
    int gh = h0 - 1 + hr, gw = w0 - 1 + wc;
    bool valid = (gh >= 0) & (gh < IW) & (gw >= 0) & (gw < IW);
    uint4v* dst = reinterpret_cast<uint4v*>(&tile[p * ROWU]);
    if (valid) {
      int gofs = gh * IW + gw;
      {
        float a0 = xb[gofs],          a1 = xb[HW + gofs];
        float a2 = xb[2 * HW + gofs], a3 = xb[3 * HW + gofs];
        float a4 = xb[4 * HW + gofs], a5 = xb[5 * HW + gofs];
        float a6 = xb[6 * HW + gofs], a7 = xb[7 * HW + gofs];
        dst[0] = uint4v{bpack2(a0, a1), bpack2(a2, a3),
                        bpack2(a4, a5), bpack2(a6, a7)};
      }
      {
        float a0 = xb[8 * HW + gofs],  a1 = xb[9 * HW + gofs];
        float a2 = xb[10 * HW + gofs], a3 = xb[11 * HW + gofs];
        float a4 = xb[12 * HW + gofs], a5 = xb[13 * HW + gofs];
        float a6 = xb[14 * HW + gofs], a7 = xb[15 * HW + gofs];
        dst[1] = uint4v{bpack2(a0, a1), bpack2(a2, a3),
                        bpack2(a4, a5), bpack2(a6, a7)};
      }
      {
        const uint4v* fp = reinterpret_cast<const uint4v*>(
            fuseP + ((size_t)bsel * HW + gofs) * 16);
        dst[2] = fp[0];
        dst[3] = fp[1];
      }
      {
        float bl0 = s_bdb[0], bl1 = s_bdb[1];
#pragma unroll
        for (int c = 0; c < 5; ++c) {
          float yv = yb[c * HW + gofs];
          bl0 = fmaf(s_bde[c], yv, bl0);
          bl1 = fmaf(s_bde[5 + c], yv, bl1);
        }
        *reinterpret_cast<float*>(&tile[p * ROWU + 32]) =
            1.f / (1.f + __expf(bl0 - bl1));
      }
    } else {
      uint4v z = {0, 0, 0, 0};
      dst[0] = z; dst[1] = z; dst[2] = z; dst[3] = z;
      *reinterpret_cast<float*>(&tile[p * ROWU + 32]) = 0.f;
    }
  }
  __syncthreads();

  // ---- compute: 8 groups, tap-major MFMA (8-way ILP) ----
  const char* tb = reinterpret_cast<const char*>(tile);
  unsigned bofs[8];
  f32x4 acc[8];
#pragma unroll
  for (int g = 0; g < 8; ++g) {
    int row = 2 * wv + (g >> 2), c0 = (g & 3) * 16;
    bofs[g] = (unsigned)((row * HLW + c0 + l15) * (ROWU * 2) + q * 16);
    acc[g] = f32x4{0.f, 0.f, 0.f, 0.f};
  }
#pragma unroll
  for (int kh = 0; kh < 3; ++kh) {
#pragma unroll
    for (int kw = 0; kw < 3; ++kw) {
      short8 a = afrag[kh * 3 + kw];
#pragma unroll
      for (int g = 0; g < 8; ++g) {
        short8 bfr = *reinterpret_cast<const short8*>(
            tb + bofs[g] + (kh * HLW + kw) * (ROWU * 2));
        acc[g] = __builtin_amdgcn_mfma_f32_16x16x32_bf16(a, bfr, acc[g], 0, 0, 0);
      }
    }
  }

  // ---- epilogue ----
  float pm0[8], pm1[8];
#pragma unroll
  for (int g = 0; g < 8; ++g) {
    float p0 = 0.f, p1 = 0.f;
#pragma unroll
    for (int j = 0; j < 4; ++j) {
      int oc = q * 4 + j;
      float fv = fmaxf(acc[g][j] + s_fcb[oc], 0.f);
      p0 = fmaf(s_fm[oc], fv, p0);
      p1 = fmaf(s_fm[16 + oc], fv, p1);
    }
    pm0[g] = p0; pm1[g] = p1;
  }
#pragma unroll
  for (int g = 0; g < 8; ++g) pm0[g] += __shfl_xor(pm0[g], 16);
#pragma unroll
  for (int g = 0; g < 8; ++g) pm1[g] += __shfl_xor(pm1[g], 16);
#pragma unroll
  for (int g = 0; g < 8; ++g) pm0[g] += __shfl_xor(pm0[g], 32);
#pragma unroll
  for (int g = 0; g < 8; ++g) pm1[g] += __shfl_xor(pm1[g], 32);

  float* outb = out + (size_t)bsel * 16 * HW;
#pragma unroll
  for (int g = 0; g < 8; ++g) {
    int row = 2 * wv + (g >> 2), c0 = (g & 3) * 16;
    int gofs = (h0 + row) * IW + w0 + c0 + l15;
    float mscale =
        1.f / (1.f + __expf((pm0[g] + s_fmb[0]) - (pm1[g] + s_fmb[1])));
    float bsc = *reinterpret_cast<const float*>(
        tb + ((row + 1) * HLW + c0 + l15 + 1) * (ROWU * 2) + 64);
    float sc = fminf(fmaxf(mscale + bsc, 0.f), 1.f);
#pragma unroll
    for (int j = 0; j < 4; ++j) {
      int oc = q * 4 + j;
      outb[(size_t)oc * HW + gofs] = fmaf(s_cv[oc], sc, s_cvb[oc]);
    }
  }
}

// ============ fallback path (ws too small): round-6 fused kernel ============
__global__ __launch_bounds__(256) void k_gap(
    const float* __restrict__ y, const float* __restrict__ fuse_w,
    const float* __restrict__ fuse_b, float* __restrict__ partial) {
  __shared__ float fw[80], fb[16];
  __shared__ float red[4][16];
  int tid = threadIdx.x;
  if (tid < 80) fw[tid] = fuse_w[tid];
  if (tid < 16) fb[tid] = fuse_b[tid];
  __syncthreads();
  int b = blockIdx.x >> 7, chunk = blockIdx.x & 127;
  const float* yb = y + (size_t)b * 5 * HW + chunk * 2048;
  float sums[16];
#pragma unroll
  for (int o = 0; o < 16; ++o) sums[o] = 0.f;
  for (int i = 0; i < 2048; i += 256) {
    int p = i + tid;
    float yv[5];
#pragma unroll
    for (int c = 0; c < 5; ++c) yv[c] = yb[c * HW + p];
#pragma unroll
    for (int o = 0; o < 16; ++o) {
      float a = fb[o];
#pragma unroll
      for (int c = 0; c < 5; ++c) a = fmaf(fw[o * 5 + c], yv[c], a);
      sums[o] += fmaxf(a, 0.f);
    }
  }
  int lane = tid & 63, wv = tid >> 6;
#pragma unroll
  for (int o = 0; o < 16; ++o) {
    float v = sums[o];
    for (int off = 32; off > 0; off >>= 1) v += __shfl_down(v, off);
    if (lane == 0) red[wv][o] = v;
  }
  __syncthreads();
  if (tid < 16)
    partial[blockIdx.x * 16 + tid] =
        red[0][tid] + red[1][tid] + red[2][tid] + red[3][tid];
}

__global__ __launch_bounds__(256) void k_main_fb(
    const float* __restrict__ x, const float* __restrict__ y,
    const float* __restrict__ fuse_w, const float* __restrict__ fuse_b,
    const unsigned short* __restrict__ wTab,
    const float* __restrict__ bd_eff, const float* __restrict__ bd_b,
    const float* __restrict__ fc_b,
    const float* __restrict__ fm_w, const float* __restrict__ fm_b,
    const float* __restrict__ cv_w, const float* __restrict__ cv_b,
    float* __restrict__ out) {
  __shared__ unsigned short tile[NHALO * ROWU];
  __shared__ float s_fw[80], s_fb[16], s_bde[10], s_bdb[2], s_fm[32],
      s_fmb[2], s_cv[16], s_cvb[16], s_fcb[16];
  int tid = threadIdx.x;
  int bsel = blockIdx.z, h0 = blockIdx.y * TH, w0 = blockIdx.x * TW;
  if (tid < 80) s_fw[tid] = fuse_w[tid];
  else if (tid < 96)  s_fb[tid - 80]   = fuse_b[tid - 80];
  else if (tid < 106) s_bde[tid - 96]  = bd_eff[bsel * 10 + tid - 96];
  else if (tid < 108) s_bdb[tid - 106] = bd_b[tid - 106];
  else if (tid < 140) s_fm[tid - 108]  = fm_w[tid - 108];
  else if (tid < 142) s_fmb[tid - 140] = fm_b[tid - 140];
  else if (tid < 158) s_cv[tid - 142]  = cv_w[tid - 142];
  else if (tid < 174) s_cvb[tid - 158] = cv_b[tid - 158];
  else if (tid < 190) s_fcb[tid - 174] = fc_b[tid - 174];
  int lane = tid & 63, wv = tid >> 6, l15 = lane & 15, q = lane >> 4;
  short8 afrag[9];
#pragma unroll
  for (int s = 0; s < 9; ++s)
    afrag[s] = *reinterpret_cast<const short8*>(wTab + (s * 16 + l15) * 32 + q * 8);
  __syncthreads();
  const float* yb = y + (size_t)bsel * 5 * HW;
  const float* xb = x + (size_t)bsel * 16 * HW;
#pragma unroll 1
  for (int p = tid; p < NHALO; p += 256) {
    int hr = p / HLW, wc = p - hr * HLW;
    int gh = h0 - 1 + hr, gw = w0 - 1 + wc;
    bool valid = (gh >= 0) & (gh < IW) & (gw >= 0) & (gw < IW);
    uint4v* dst = reinterpret_cast<uint4v*>(&tile[p * ROWU]);
    if (valid) {
      int gofs = gh * IW + gw;
      {
        float a0 = xb[gofs],          a1 = xb[HW + gofs];
        float a2 = xb[2 * HW + gofs], a3 = xb[3 * HW + gofs];
        float a4 = xb[4 * HW + gofs], a5 = xb[5 * HW + gofs];
        float a6 = xb[6 * HW + gofs], a7 = xb[7 * HW + gofs];
        dst[0] = uint4v{bpack2(a0, a1), bpack2(a2, a3),
                        bpack2(a4, a5), bpack2(a6, a7)};
      }
      {
        float a0 = xb[8 * HW + gofs],  a1 = xb[9 * HW + gofs];
        float a2 = xb[10 * HW + gofs], a3 = xb[11 * HW + gofs];
        float a4 = xb[12 * HW + gofs], a5 = xb[13 * HW + gofs];
        float a6 = xb[14 * HW + gofs], a7 = xb[15 * HW + gofs];
        dst[1] = uint4v{bpack2(a0, a1), bpack2(a2, a3),
                        bpack2(a4, a5), bpack2(a6, a7)};
      }
      float yv[5];
#pragma unroll
      for (int c = 0; c < 5; ++c) yv[c] = yb[c * HW + gofs];
      float fo[8];
#pragma unroll
      for (int o = 0; o < 8; ++o) {
        float a = s_fb[o];
#pragma unroll
        for (int c = 0; c < 5; ++c) a = fmaf(s_fw[o * 5 + c], yv[c], a);
        fo[o] = fmaxf(a, 0.f);
      }
      dst[2] = uint4v{bpack2(fo[0], fo[1]), bpack2(fo[2], fo[3]),
                      bpack2(fo[4], fo[5]), bpack2(fo[6], fo[7])};
#pragma unroll
      for (int o = 0; o < 8; ++o) {
        float a = s_fb[8 + o];
#pragma unroll
        for (int c = 0; c < 5; ++c) a = fmaf(s_fw[(8 + o) * 5 + c], yv[c], a);
        fo[o] = fmaxf(a, 0.f);
      }
      dst[3] = uint4v{bpack2(fo[0], fo[1]), bpack2(fo[2], fo[3]),
                      bpack2(fo[4], fo[5]), bpack2(fo[6], fo[7])};
      float bl0 = s_bdb[0], bl1 = s_bdb[1];
#pragma unroll
      for (int c = 0; c < 5; ++c) {
        bl0 = fmaf(s_bde[c], yv[c], bl0);
        bl1 = fmaf(s_bde[5 + c], yv[c], bl1);
      }
      *reinterpret_cast<float*>(&tile[p * ROWU + 32]) =
          1.f / (1.f + __expf(bl0 - bl1));
    } else {
      uint4v z = {0, 0, 0, 0};
      dst[0] = z; dst[1] = z; dst[2] = z; dst[3] = z;
      *reinterpret_cast<float*>(&tile[p * ROWU + 32]) = 0.f;
    }
  }
  __syncthreads();
  const char* tb = reinterpret_cast<const char*>(tile);
  unsigned bofs[8];
  f32x4 acc[8];
#pragma unroll
  for (int g = 0; g < 8; ++g) {
    int row = 2 * wv + (g >> 2), c0 = (g & 3) * 16;
    bofs[g] = (unsigned)((row * HLW + c0 + l15) * (ROWU * 2) + q * 16);
    acc[g] = f32x4{0.f, 0.f, 0.f, 0.f};
  }
#pragma unroll
  for (int kh = 0; kh < 3; ++kh) {
#pragma unroll
    for (int kw = 0; kw < 3; ++kw) {
      short8 a = afrag[kh * 3 + kw];
#pragma unroll
      for (int g = 0; g < 8; ++g) {
        short8 bfr = *reinterpret_cast<const short8*>(
            tb + bofs[g] + (kh * HLW + kw) * (ROWU * 2));
        acc[g] = __builtin_amdgcn_mfma_f32_16x16x32_bf16(a, bfr, acc[g], 0, 0, 0);
      }
    }
  }
  float pm0[8], pm1[8];
#pragma unroll
  for (int g = 0; g < 8; ++g) {
    float p0 = 0.f, p1 = 0.f;
#pragma unroll
    for (int j = 0; j < 4; ++j) {
      int oc = q * 4 + j;
      float fv = fmaxf(acc[g][j] + s_fcb[oc], 0.f);
      p0 = fmaf(s_fm[oc], fv, p0);
      p1 = fmaf(s_fm[16 + oc], fv, p1);
    }
    pm0[g] = p0; pm1[g] = p1;
  }
#pragma unroll
  for (int g = 0; g < 8; ++g) pm0[g] += __shfl_xor(pm0[g], 16);
#pragma unroll
  for (int g = 0; g < 8; ++g) pm1[g] += __shfl_xor(pm1[g], 16);
#pragma unroll
  for (int g = 0; g < 8; ++g) pm0[g] += __shfl_xor(pm0[g], 32);
#pragma unroll
  for (int g = 0; g < 8; ++g) pm1[g] += __shfl_xor(pm1[g], 32);
  float* outb = out + (size_t)bsel * 16 * HW;
#pragma unroll
  for (int g = 0; g < 8; ++g) {
    int row = 2 * wv + (g >> 2), c0 = (g & 3) * 16;
    int gofs = (h0 + row) * IW + w0 + c0 + l15;
    float mscale =
        1.f / (1.f + __expf((pm0[g] + s_fmb[0]) - (pm1[g] + s_fmb[1])));
    float bsc = *reinterpret_cast<const float*>(
        tb + ((row + 1) * HLW + c0 + l15 + 1) * (ROWU * 2) + 64);
    float sc = fminf(fmaxf(mscale + bsc, 0.f), 1.f);
#pragma unroll
    for (int j = 0; j < 4; ++j) {
      int oc = q * 4 + j;
      outb[(size_t)oc * HW + gofs] = fmaf(s_cv[oc], sc, s_cvb[oc]);
    }
  }
}

extern "C" void kernel_launch(void* const* d_in, const int* in_sizes, int n_in,
                              void* d_out, int out_size, void* d_ws, size_t ws_size,
                              hipStream_t stream) {
  const float* x      = (const float*)d_in[0];
  const float* y      = (const float*)d_in[1];
  const float* fuse_w = (const float*)d_in[2];
  const float* fuse_b = (const float*)d_in[3];
  const float* se_w1  = (const float*)d_in[4];
  const float* se_w2  = (const float*)d_in[5];
  const float* bd_w   = (const float*)d_in[6];
  const float* bd_b   = (const float*)d_in[7];
  const float* fc_w   = (const float*)d_in[8];
  const float* fc_b   = (const float*)d_in[9];
  const float* fm_w   = (const float*)d_in[10];
  const float* fm_b   = (const float*)d_in[11];
  const float* cv_w   = (const float*)d_in[12];
  const float* cv_b   = (const float*)d_in[13];
  float* out = (float*)d_out;

  char* ws = (char*)d_ws;
  float* partial = (float*)ws;                          // 64 KB
  float* bd_eff  = partial + 1024 * 16;                 // 320 B
  unsigned short* wTab = (unsigned short*)(ws + 65856); // 9216 B
  size_t off = 75264;                                   // 256-aligned
  unsigned short* fuseP = (unsigned short*)(ws + off);  // 2M px * 32 B = 67.1 MB
  size_t need = off + (size_t)8 * HW * 32;

  if (ws_size >= need) {
    k_fuse<<<1024, 256, 0, stream>>>(y, fuse_w, fuse_b, fuseP, partial);
    k_se2<<<1, 256, 0, stream>>>(partial, se_w1, se_w2, bd_w, fc_w, bd_eff,
                                 wTab);
    k_main3<<<dim3(8, 64, 8), 256, 0, stream>>>(
        x, y, fuseP, wTab, bd_eff, bd_b, fc_b, fm_w, fm_b, cv_w, cv_b, out);
  } else {
    k_gap<<<1024, 256, 0, stream>>>(y, fuse_w, fuse_b, partial);
    k_se2<<<1, 256, 0, stream>>>(partial, se_w1, se_w2, bd_w, fc_w, bd_eff,
                                 wTab);
    k_main_fb<<<dim3(8, 64, 8), 256, 0, stream>>>(
        x, y, fuse_w, fuse_b, wTab, bd_eff, bd_b, fc_b, fm_w, fm_b, cv_w, cv_b,
        out);
  }
}